// Round 12
// baseline (121.099 us; speedup 1.0000x reference)
//
#include <hip/hip_runtime.h>

#define BATCH 16
#define SEQ   4096
#define DIM   64
#define WIN   512

constexpr int BM = 64;        // q rows per block: 2 waves x 32 q-rows each
constexpr int BN = 64;        // keys per tile
constexpr int NTHREADS = 128; // 2 waves
constexpr int NTILES = SEQ / BN;      // 64
constexpr int TILEB  = 8192;          // one 64x64 f16 tile (K or VT), swizzled
constexpr int BUFB   = 2 * TILEB;     // K + VT per buffer
constexpr int SMEMB  = 2 * BUFB;      // 32768 -> 4 blocks/CU (128KB/160KB)

constexpr float QSCALE  = 0.125f * 1.44269504088896340736f;
constexpr float MASKVAL = -3.0e38f;
constexpr float DEFER_THR = 8.0f;

typedef _Float16 f16x2 __attribute__((ext_vector_type(2)));
typedef _Float16 f16x4 __attribute__((ext_vector_type(4)));
typedef _Float16 f16x8 __attribute__((ext_vector_type(8)));
typedef float    f32x4 __attribute__((ext_vector_type(4)));

__device__ __forceinline__ f16x2 pk2(float a, float b) {
    return __builtin_bit_cast(f16x2, __builtin_amdgcn_cvt_pkrtz(a, b));
}

// global->LDS direct DMA, 16B per lane; LDS dest = (wave-uniform base) + lane*16
__device__ __forceinline__ void gl16(const char* g, char* l) {
    __builtin_amdgcn_global_load_lds(
        (const __attribute__((address_space(1))) unsigned int*)g,
        (__attribute__((address_space(3))) unsigned int*)l, 16, 0, 0);
}

// ---------------- pre-pass (byte-identical to R11, verified) ----------------
// K16: [b][tile][64 rows][128B], 16B-chunk XOR-swizzled: chunk ^= (row&7)
// VT16: [b][tile][panel(key>>4)][64 d][16 key x 2B], 8B-chunk swz: j ^= (d>>2)&3
__global__ __launch_bounds__(256)
void prep_kernel(const float* __restrict__ kg, const float* __restrict__ vg,
                 _Float16* __restrict__ k16, _Float16* __restrict__ vt16) {
    const int t    = threadIdx.x;
    const int b    = blockIdx.y;
    const int tile = blockIdx.x;
    const int s0   = tile * 64;

    {
        const int rb    = t >> 4;
        const int c4    = (t & 15) * 4;
        const int chunk = c4 >> 3;
        const int half  = (c4 >> 2) & 1;
        char* kout = (char*)k16 + ((size_t)b * NTILES + tile) * TILEB;
        #pragma unroll
        for (int i = 0; i < 4; ++i) {
            const int row = rb + i * 16;
            const float4 x = *(const float4*)&kg[((size_t)b * SEQ + s0 + row) * DIM + c4];
            union { f16x4 v; f16x2 h[2]; } u;
            u.h[0] = pk2(x.x, x.y); u.h[1] = pk2(x.z, x.w);
            *(f16x4*)(kout + row * 128 + ((chunk ^ (row & 7)) << 4) + half * 8) = u.v;
        }
    }
    {
        const int d   = t >> 2;
        const int j   = t & 3;
        const int swz = (j ^ ((d >> 2) & 3)) << 3;
        char* vout = (char*)vt16 + ((size_t)b * NTILES + tile) * TILEB;
        #pragma unroll
        for (int p = 0; p < 4; ++p) {
            const size_t kr = (size_t)b * SEQ + s0 + p * 16 + 4 * j;
            const float x0 = vg[(kr + 0) * DIM + d];
            const float x1 = vg[(kr + 1) * DIM + d];
            const float x2 = vg[(kr + 2) * DIM + d];
            const float x3 = vg[(kr + 3) * DIM + d];
            union { f16x4 v; f16x2 h[2]; } u;
            u.h[0] = pk2(x0, x1); u.h[1] = pk2(x2, x3);
            *(f16x4*)(vout + p * 2048 + d * 32 + swz) = u.v;
        }
    }
}

// ---------------- main: 2 waves x 32 q-rows; DMA staging; 1 barrier/round ----
__global__ __launch_bounds__(NTHREADS, 2)
void swa_main(const float* __restrict__ qg, float* __restrict__ outg,
              const _Float16* __restrict__ k16, const _Float16* __restrict__ vt16) {
    __shared__ __align__(16) char smem[SMEMB];

    const int tid  = threadIdx.x;
    const int lane = tid & 63;
    const int wave = tid >> 6;     // 0..1
    const int lr   = lane & 15;
    const int quad = lane >> 4;

    // chunked XCD swizzle: 8 consecutive qblks of one batch per XCD chunk
    static_assert(SEQ / BM == 64 && BATCH == 16, "swizzle assumes 1024 blocks");
    const int lin    = blockIdx.x;         // 0..1023
    const int xcd    = lin & 7;
    const int slot   = lin >> 3;
    const int member = slot & 7;
    const int gchunk = (slot >> 3) * 8 + xcd;      // bijective
    const int b      = gchunk >> 3;
    const int qblk   = (gchunk & 7) * 8 + member;

    const int qrow0 = qblk * BM;
    const int wr0   = qrow0 + wave * 32;   // 32 q-rows per wave
    const int q0    = wr0 + lr;
    const int q1    = wr0 + 16 + lr;

    const float* qb  = qg + (size_t)b * SEQ * DIM;
    float*       ob  = outg + (size_t)b * SEQ * DIM;
    const char*  kbb = (const char*)k16 + (size_t)b * NTILES * TILEB;
    const char*  vbb = (const char*)vt16 + (size_t)b * NTILES * TILEB;

    // swizzled LDS lane bases (loop offsets fold into ds_read immediates)
    const int kaddr0 = lr * 128 + (((quad    ) ^ (lr & 7)) << 4);
    const int kaddr1 = lr * 128 + (((quad + 4) ^ (lr & 7)) << 4);
    const int vaddr  = lr * 32 + ((quad ^ (lr >> 2)) << 3);
    const int dmaoff = wave * 4096 + lane * 16;    // per-wave half-tile slice

    // ---- Q B-frags for both q-tiles ----
    f16x8 qfA0, qfA1, qfB0, qfB1;
    {
        const float* qp = qb + (size_t)q0 * DIM + quad * 8;
        const float4 a0 = *(const float4*)(qp + 0);
        const float4 a1 = *(const float4*)(qp + 4);
        const float4 a2 = *(const float4*)(qp + 32);
        const float4 a3 = *(const float4*)(qp + 36);
        union { f16x8 v; f16x2 h[4]; } u0, u1;
        u0.h[0] = pk2(a0.x * QSCALE, a0.y * QSCALE);
        u0.h[1] = pk2(a0.z * QSCALE, a0.w * QSCALE);
        u0.h[2] = pk2(a1.x * QSCALE, a1.y * QSCALE);
        u0.h[3] = pk2(a1.z * QSCALE, a1.w * QSCALE);
        u1.h[0] = pk2(a2.x * QSCALE, a2.y * QSCALE);
        u1.h[1] = pk2(a2.z * QSCALE, a2.w * QSCALE);
        u1.h[2] = pk2(a3.x * QSCALE, a3.y * QSCALE);
        u1.h[3] = pk2(a3.z * QSCALE, a3.w * QSCALE);
        qfA0 = u0.v; qfA1 = u1.v;
    }
    {
        const float* qp = qb + (size_t)q1 * DIM + quad * 8;
        const float4 a0 = *(const float4*)(qp + 0);
        const float4 a1 = *(const float4*)(qp + 4);
        const float4 a2 = *(const float4*)(qp + 32);
        const float4 a3 = *(const float4*)(qp + 36);
        union { f16x8 v; f16x2 h[4]; } u0, u1;
        u0.h[0] = pk2(a0.x * QSCALE, a0.y * QSCALE);
        u0.h[1] = pk2(a0.z * QSCALE, a0.w * QSCALE);
        u0.h[2] = pk2(a1.x * QSCALE, a1.y * QSCALE);
        u0.h[3] = pk2(a1.z * QSCALE, a1.w * QSCALE);
        u1.h[0] = pk2(a2.x * QSCALE, a2.y * QSCALE);
        u1.h[1] = pk2(a2.z * QSCALE, a2.w * QSCALE);
        u1.h[2] = pk2(a3.x * QSCALE, a3.y * QSCALE);
        u1.h[3] = pk2(a3.z * QSCALE, a3.w * QSCALE);
        qfB0 = u0.v; qfB1 = u1.v;
    }

    f32x4 o0[4], o1[4];
    #pragma unroll
    for (int mi = 0; mi < 4; ++mi) {
        o0[mi] = (f32x4){0.f, 0.f, 0.f, 0.f};
        o1[mi] = (f32x4){0.f, 0.f, 0.f, 0.f};
    }
    float m0 = -1e30f, l0 = 0.f, m1 = -1e30f, l1 = 0.f;

    const int t0 = (qrow0 > (WIN - 1)) ? (qrow0 - (WIN - 1)) >> 6 : 0;
    const int t1 = (qrow0 + BM - 1) >> 6;   // == qblk

    // ---- prologue: DMA tile t0 into buffer 0 ----
    {
        const char* gK = kbb + (size_t)t0 * TILEB;
        const char* gV = vbb + (size_t)t0 * TILEB;
        #pragma unroll
        for (int c = 0; c < 4; ++c) {
            gl16(gK + dmaoff + c * 1024, smem + wave * 4096 + lane * 16 + c * 1024);
            gl16(gV + dmaoff + c * 1024, smem + TILEB + wave * 4096 + lane * 16 + c * 1024);
        }
    }
    __syncthreads();

    for (int t = t0; t <= t1; ++t) {
        const int cb = (t - t0) & 1;
        const char* Kc = smem + cb * BUFB;
        const char* Vc = Kc + TILEB;

        // issue next tile's DMA first; completes under this round's compute
        if (t < t1) {
            char* nb = smem + (cb ^ 1) * BUFB;
            const char* gK = kbb + (size_t)(t + 1) * TILEB;
            const char* gV = vbb + (size_t)(t + 1) * TILEB;
            #pragma unroll
            for (int c = 0; c < 4; ++c) {
                gl16(gK + dmaoff + c * 1024, nb + wave * 4096 + lane * 16 + c * 1024);
                gl16(gV + dmaoff + c * 1024, nb + TILEB + wave * 4096 + lane * 16 + c * 1024);
            }
        }

        const int kbase = t * BN;
        const int u     = (wr0 - kbase) >> 4;          // q rows wr0..wr0+31
        const int mtlo  = (u - 32 > 0) ? u - 32 : 0;
        const int mthi  = (u + 1 < 3) ? u + 1 : 3;

        if (mtlo <= mthi) {
            // ---- S^T = K * Q^T: K-frag read ONCE, feeds both q-tiles ----
            f32x4 sc0[4], sc1[4];
            #pragma unroll
            for (int mt = 0; mt < 4; ++mt) {
                if (mt >= mtlo && mt <= mthi) {
                    const f16x8 kf0 = *(const f16x8*)(Kc + mt * 2048 + kaddr0);
                    const f16x8 kf1 = *(const f16x8*)(Kc + mt * 2048 + kaddr1);
                    f32x4 s = (f32x4){0.f, 0.f, 0.f, 0.f};
                    s = __builtin_amdgcn_mfma_f32_16x16x32_f16(kf0, qfA0, s, 0, 0, 0);
                    s = __builtin_amdgcn_mfma_f32_16x16x32_f16(kf1, qfA1, s, 0, 0, 0);
                    sc0[mt] = s;
                    f32x4 r = (f32x4){0.f, 0.f, 0.f, 0.f};
                    r = __builtin_amdgcn_mfma_f32_16x16x32_f16(kf0, qfB0, r, 0, 0, 0);
                    r = __builtin_amdgcn_mfma_f32_16x16x32_f16(kf1, qfB1, r, 0, 0, 0);
                    sc1[mt] = r;
                }
            }

            // ---- mask only window-edge rounds (wave-uniform) ----
            const bool edge = ((wr0 + 31) - (kbase + mtlo * 16) >= WIN) ||
                              ((kbase + mthi * 16 + 15) > wr0);
            if (edge) {
                #pragma unroll
                for (int mt = 0; mt < 4; ++mt) {
                    if (mt >= mtlo && mt <= mthi) {
                        #pragma unroll
                        for (int r = 0; r < 4; ++r) {
                            const int key = kbase + mt * 16 + quad * 4 + r;
                            sc0[mt][r] = ((unsigned)(q0 - key) < (unsigned)WIN) ? sc0[mt][r] : MASKVAL;
                            sc1[mt][r] = ((unsigned)(q1 - key) < (unsigned)WIN) ? sc1[mt][r] : MASKVAL;
                        }
                    }
                }
            }

            // ---- shuffle-free common-path online softmax, per q-tile ----
            f16x4 pb0[4], pb1[4];
            {
                float pm = MASKVAL;
                #pragma unroll
                for (int mt = 0; mt < 4; ++mt)
                    if (mt >= mtlo && mt <= mthi)
                        pm = fmaxf(pm, fmaxf(fmaxf(sc0[mt][0], sc0[mt][1]),
                                             fmaxf(sc0[mt][2], sc0[mt][3])));
                if (__any(pm > m0 + DEFER_THR)) {
                    float pmf = fmaxf(pm, __shfl_xor(pm, 16));
                    pmf = fmaxf(pmf, __shfl_xor(pmf, 32));
                    const float mn    = fmaxf(m0, pmf);
                    const float alpha = exp2f(m0 - mn);
                    m0 = mn; l0 *= alpha;
                    #pragma unroll
                    for (int mi = 0; mi < 4; ++mi) o0[mi] = o0[mi] * alpha;
                }
                float ls = 0.f;
                #pragma unroll
                for (int nt = 0; nt < 4; ++nt) {
                    if (nt >= mtlo && nt <= mthi) {
                        const float p0 = exp2f(sc0[nt][0] - m0);
                        const float p1 = exp2f(sc0[nt][1] - m0);
                        const float p2 = exp2f(sc0[nt][2] - m0);
                        const float p3 = exp2f(sc0[nt][3] - m0);
                        ls += (p0 + p1) + (p2 + p3);
                        union { f16x4 v; f16x2 h[2]; } up;
                        up.h[0] = pk2(p0, p1);
                        up.h[1] = pk2(p2, p3);
                        pb0[nt] = up.v;
                    }
                }
                l0 += ls;
            }
            {
                float pm = MASKVAL;
                #pragma unroll
                for (int mt = 0; mt < 4; ++mt)
                    if (mt >= mtlo && mt <= mthi)
                        pm = fmaxf(pm, fmaxf(fmaxf(sc1[mt][0], sc1[mt][1]),
                                             fmaxf(sc1[mt][2], sc1[mt][3])));
                if (__any(pm > m1 + DEFER_THR)) {
                    float pmf = fmaxf(pm, __shfl_xor(pm, 16));
                    pmf = fmaxf(pmf, __shfl_xor(pmf, 32));
                    const float mn    = fmaxf(m1, pmf);
                    const float alpha = exp2f(m1 - mn);
                    m1 = mn; l1 *= alpha;
                    #pragma unroll
                    for (int mi = 0; mi < 4; ++mi) o1[mi] = o1[mi] * alpha;
                }
                float ls = 0.f;
                #pragma unroll
                for (int nt = 0; nt < 4; ++nt) {
                    if (nt >= mtlo && nt <= mthi) {
                        const float p0 = exp2f(sc1[nt][0] - m1);
                        const float p1 = exp2f(sc1[nt][1] - m1);
                        const float p2 = exp2f(sc1[nt][2] - m1);
                        const float p3 = exp2f(sc1[nt][3] - m1);
                        ls += (p0 + p1) + (p2 + p3);
                        union { f16x4 v; f16x2 h[2]; } up;
                        up.h[0] = pk2(p0, p1);
                        up.h[1] = pk2(p2, p3);
                        pb1[nt] = up.v;
                    }
                }
                l1 += ls;
            }

            // ---- O^T += V^T * P^T: V-frag read ONCE, feeds both q-tiles ----
            #pragma unroll
            for (int nt = 0; nt < 4; ++nt) {
                if (nt >= mtlo && nt <= mthi) {
                    #pragma unroll
                    for (int mi = 0; mi < 4; ++mi) {
                        const f16x4 vf = *(const f16x4*)(Vc + nt * 2048 + mi * 512 + vaddr);
                        o0[mi] = __builtin_amdgcn_mfma_f32_16x16x16f16(vf, pb0[nt], o0[mi], 0, 0, 0);
                        o1[mi] = __builtin_amdgcn_mfma_f32_16x16x16f16(vf, pb1[nt], o1[mi], 0, 0, 0);
                    }
                }
            }
        }

        __syncthreads();   // waits own DMAs (vmcnt 0) + publishes buffer
    }

    // ---- epilogue per q-tile: l reduce, normalize, direct stores ----
    {
        float l = l0;
        l += __shfl_xor(l, 16);
        l += __shfl_xor(l, 32);
        const float inv = 1.0f / l;
        #pragma unroll
        for (int mi = 0; mi < 4; ++mi) {
            float4 st;
            st.x = o0[mi][0] * inv; st.y = o0[mi][1] * inv;
            st.z = o0[mi][2] * inv; st.w = o0[mi][3] * inv;
            *(float4*)&ob[(size_t)q0 * DIM + mi * 16 + quad * 4] = st;
        }
    }
    {
        float l = l1;
        l += __shfl_xor(l, 16);
        l += __shfl_xor(l, 32);
        const float inv = 1.0f / l;
        #pragma unroll
        for (int mi = 0; mi < 4; ++mi) {
            float4 st;
            st.x = o1[mi][0] * inv; st.y = o1[mi][1] * inv;
            st.z = o1[mi][2] * inv; st.w = o1[mi][3] * inv;
            *(float4*)&ob[(size_t)q1 * DIM + mi * 16 + quad * 4] = st;
        }
    }
}

extern "C" void kernel_launch(void* const* d_in, const int* in_sizes, int n_in,
                              void* d_out, int out_size, void* d_ws, size_t ws_size,
                              hipStream_t stream) {
    (void)in_sizes; (void)n_in; (void)out_size; (void)ws_size;
    const float* q = (const float*)d_in[0];
    const float* k = (const float*)d_in[1];
    const float* v = (const float*)d_in[2];
    float* out = (float*)d_out;

    const size_t KVB = (size_t)BATCH * SEQ * DIM * sizeof(_Float16);  // 8.39 MB
    _Float16* vt16 = (_Float16*)d_ws;
    _Float16* k16  = (_Float16*)((char*)d_ws + KVB);

    prep_kernel<<<dim3(NTILES, BATCH), dim3(256), 0, stream>>>(k, v, k16, vt16);
    swa_main<<<dim3(BATCH * SEQ / BM), dim3(NTHREADS), 0, stream>>>(q, out, k16, vt16);
}